// Round 1
// baseline (195.318 us; speedup 1.0000x reference)
//
#include <hip/hip_runtime.h>
#include <hip/hip_bf16.h>

#define TILE 128
#define PAD  140   // halfs per h-row in LDS: 280B stride -> conflict-free b64 A-reads

typedef _Float16 half8 __attribute__((ext_vector_type(8)));
typedef _Float16 half4 __attribute__((ext_vector_type(4)));
typedef float    f32x4 __attribute__((ext_vector_type(4)));

// ws layout (halfs): [0,16384) L1 frags, [16384,32768) L2, [32768,49152) L3, [49152,51200) W4
// fragment (nt,ks), lane l, elem j holds W[k][n], n = nt*16+(l&15),
// k = ks*32 + 16*(j>>2) + ((l>>4)<<2) + (j&3)   (same permutation used for A-frags)
__global__ __launch_bounds__(256) void prep_kernel(
    const float* __restrict__ W1, const float* __restrict__ W2,
    const float* __restrict__ W3, const float* __restrict__ W4,
    _Float16* __restrict__ out)
{
    int t = blockIdx.x * blockDim.x + threadIdx.x;
    if (t >= 6400) return;
    int lane = t & 63;
    int frag = t >> 6;                 // 0..99
    const float* W; _Float16* dst; int nt, ks, ncols;
    if (frag < 96) {
        int l = frag >> 5, f = frag & 31;
        W = (l == 0) ? W1 : (l == 1) ? W2 : W3;
        nt = f >> 2; ks = f & 3; ncols = 128;
        dst = out + l * 16384 + f * 512 + lane * 8;
    } else {
        int f = frag - 96;
        W = W4; nt = 0; ks = f; ncols = 14;
        dst = out + 49152 + f * 512 + lane * 8;
    }
    int n = nt * 16 + (lane & 15);
    int kbase = ks * 32 + ((lane >> 4) << 2);
#pragma unroll
    for (int j = 0; j < 8; ++j) {
        int k = kbase + ((j >> 2) << 4) + (j & 3);
        float v = (n < ncols) ? W[k * ncols + n] : 0.0f;
        dst[j] = (_Float16)v;
    }
}

__global__ __launch_bounds__(256, 2) void nflow_kernel(
    const float* __restrict__ x, const float* __restrict__ z,
    const float* __restrict__ W0, const float* __restrict__ b0,
    const float* __restrict__ b1, const float* __restrict__ b2,
    const float* __restrict__ b3, const float* __restrict__ b4v,
    const _Float16* __restrict__ Bf, float* __restrict__ y, int N)
{
    __shared__ _Float16 hbuf[2][TILE * PAD];   // 71680 B
    __shared__ float    phis[TILE * 17];       //  8704 B

    const int tid  = threadIdx.x;
    const int lane = tid & 63;
    const int wid  = tid >> 6;
    const int lr   = lane & 15;
    const int lg   = lane >> 4;
    const int base = blockIdx.x * TILE;
    const int mt0  = wid * 2;

    // ---- layer 0: h0 = relu(x*W0 + b0), 1 -> 128 (elementwise)
    {
        int s  = tid >> 1;
        int f0 = (tid & 1) * 64;
        int gs = base + s;
        float xv = (gs < N) ? x[gs] : 0.0f;
#pragma unroll
        for (int c = 0; c < 16; ++c) {
            half4 hv;
#pragma unroll
            for (int e = 0; e < 4; ++e) {
                int j = f0 + c * 4 + e;
                float h = fmaxf(fmaf(xv, W0[j], b0[j]), 0.0f);
                hv[e] = (_Float16)h;
            }
            *(half4*)&hbuf[0][s * PAD + f0 + c * 4] = hv;
        }
    }
    __syncthreads();

    // ---- hidden layers 1..3: 128 -> 128 via MFMA 16x16x32 f16
    int cur = 0;
#pragma unroll
    for (int l = 0; l < 3; ++l) {
        const float* bias = (l == 0) ? b1 : (l == 1) ? b2 : b3;

        half8 a[2][4];
#pragma unroll
        for (int mi = 0; mi < 2; ++mi) {
            int m = (mt0 + mi) * 16 + lr;
#pragma unroll
            for (int ks = 0; ks < 4; ++ks) {
                int k0 = ks * 32 + lg * 4;
                half4 lo = *(const half4*)&hbuf[cur][m * PAD + k0];
                half4 hi = *(const half4*)&hbuf[cur][m * PAD + k0 + 16];
#pragma unroll
                for (int e = 0; e < 4; ++e) { a[mi][ks][e] = lo[e]; a[mi][ks][e + 4] = hi[e]; }
            }
        }

        f32x4 acc[2][8];
#pragma unroll
        for (int mi = 0; mi < 2; ++mi)
#pragma unroll
            for (int nt = 0; nt < 8; ++nt)
                acc[mi][nt] = (f32x4){0.f, 0.f, 0.f, 0.f};

        const half8* Bl = (const half8*)Bf + l * 2048;
#pragma unroll
        for (int nt = 0; nt < 8; ++nt) {
            half8 bfr[4];
#pragma unroll
            for (int ks = 0; ks < 4; ++ks) bfr[ks] = Bl[(nt * 4 + ks) * 64 + lane];
#pragma unroll
            for (int mi = 0; mi < 2; ++mi)
#pragma unroll
                for (int ks = 0; ks < 4; ++ks)
                    acc[mi][nt] = __builtin_amdgcn_mfma_f32_16x16x32_f16(a[mi][ks], bfr[ks], acc[mi][nt], 0, 0, 0);
        }

        int nxt = cur ^ 1;
#pragma unroll
        for (int mi = 0; mi < 2; ++mi)
#pragma unroll
            for (int nt = 0; nt < 8; ++nt) {
                float bn = bias[nt * 16 + lr];
#pragma unroll
                for (int r = 0; r < 4; ++r) {
                    float v = fmaxf(acc[mi][nt][r] + bn, 0.0f);
                    hbuf[nxt][((mt0 + mi) * 16 + lg * 4 + r) * PAD + nt * 16 + lr] = (_Float16)v;
                }
            }
        __syncthreads();
        cur = nxt;
    }

    // ---- layer 4: phi = h @ W4 + b4  (128 -> 14, N padded to 16)
    {
        f32x4 acc4[2];
        acc4[0] = (f32x4){0.f, 0.f, 0.f, 0.f};
        acc4[1] = (f32x4){0.f, 0.f, 0.f, 0.f};
        const half8* B4 = (const half8*)Bf + 6144;
        half8 bfr[4];
#pragma unroll
        for (int ks = 0; ks < 4; ++ks) bfr[ks] = B4[ks * 64 + lane];
#pragma unroll
        for (int mi = 0; mi < 2; ++mi) {
            int m = (mt0 + mi) * 16 + lr;
#pragma unroll
            for (int ks = 0; ks < 4; ++ks) {
                int k0 = ks * 32 + lg * 4;
                half4 lo = *(const half4*)&hbuf[cur][m * PAD + k0];
                half4 hi = *(const half4*)&hbuf[cur][m * PAD + k0 + 16];
                half8 av;
#pragma unroll
                for (int e = 0; e < 4; ++e) { av[e] = lo[e]; av[e + 4] = hi[e]; }
                acc4[mi] = __builtin_amdgcn_mfma_f32_16x16x32_f16(av, bfr[ks], acc4[mi], 0, 0, 0);
            }
        }
        float bn = (lr < 14) ? b4v[lr] : 0.0f;
#pragma unroll
        for (int mi = 0; mi < 2; ++mi)
#pragma unroll
            for (int r = 0; r < 4; ++r)
                phis[((mt0 + mi) * 16 + lg * 4 + r) * 17 + lr] = acc4[mi][r] + bn;
    }
    __syncthreads();

    // ---- RQS inverse (fp32, per sample; all indices static after unroll)
    if (tid < TILE) {
        int gs = base + tid;
        if (gs < N) {
            const float* ph = &phis[tid * 17];
            float mw = ph[0], mh = ph[5];
#pragma unroll
            for (int i = 1; i < 5; ++i) { mw = fmaxf(mw, ph[i]); mh = fmaxf(mh, ph[5 + i]); }
            float ew[5], eh[5];
            float sw = 0.f, sh = 0.f;
#pragma unroll
            for (int i = 0; i < 5; ++i) {
                ew[i] = expf(ph[i] - mw);      sw += ew[i];
                eh[i] = expf(ph[5 + i] - mh);  sh += eh[i];
            }
            float iw = 10.0f / sw, ih = 10.0f / sh;
            float xk[6], yk[6], dk[6];
            xk[0] = -5.0f; yk[0] = -5.0f;
#pragma unroll
            for (int i = 0; i < 5; ++i) {
                xk[i + 1] = xk[i] + ew[i] * iw;
                yk[i + 1] = yk[i] + eh[i] * ih;
            }
            dk[0] = 1.0f; dk[5] = 1.0f;
#pragma unroll
            for (int i = 0; i < 4; ++i) {
                float v = ph[10 + i];
                dk[i + 1] = 0.0001f + fmaxf(v, 0.0f) + log1pf(expf(-fabsf(v)));
            }
            float zv = z[gs];
            float zc = fminf(fmaxf(zv, -5.0f), 5.0f);
            int k = 0;
#pragma unroll
            for (int i = 1; i <= 4; ++i) k += (zc >= yk[i]) ? 1 : 0;
            float x0 = xk[0], x1 = xk[1], y0 = yk[0], y1 = yk[1], d0 = dk[0], d1 = dk[1];
#pragma unroll
            for (int i = 1; i < 5; ++i)
                if (k == i) { x0 = xk[i]; x1 = xk[i + 1]; y0 = yk[i]; y1 = yk[i + 1]; d0 = dk[i]; d1 = dk[i + 1]; }
            float dx = x1 - x0, dy = y1 - y0;
            float s  = dy / dx;
            float tt = zc - y0;
            float mm = d0 + d1 - 2.0f * s;
            float aa = dy * (s - d0) + tt * mm;
            float bb = dy * d0 - tt * mm;
            float cc = -s * tt;
            float disc = fmaxf(bb * bb - 4.0f * aa * cc, 0.0f);
            float xi   = (2.0f * cc) / (-bb - sqrtf(disc));
            float xin  = x0 + xi * dx;
            y[gs] = (fabsf(zv) >= 5.0f) ? zv : xin;
        }
    }
}

extern "C" void kernel_launch(void* const* d_in, const int* in_sizes, int n_in,
                              void* d_out, int out_size, void* d_ws, size_t ws_size,
                              hipStream_t stream) {
    const float* x  = (const float*)d_in[0];
    const float* z  = (const float*)d_in[1];
    const float* W0 = (const float*)d_in[2];
    const float* b0 = (const float*)d_in[3];
    const float* W1 = (const float*)d_in[4];
    const float* b1 = (const float*)d_in[5];
    const float* W2 = (const float*)d_in[6];
    const float* b2 = (const float*)d_in[7];
    const float* W3 = (const float*)d_in[8];
    const float* b3 = (const float*)d_in[9];
    const float* W4 = (const float*)d_in[10];
    const float* b4 = (const float*)d_in[11];
    float* y = (float*)d_out;
    int N = in_sizes[0];

    _Float16* wsH = (_Float16*)d_ws;
    prep_kernel<<<25, 256, 0, stream>>>(W1, W2, W3, W4, wsH);
    int nblk = (N + TILE - 1) / TILE;
    nflow_kernel<<<nblk, 256, 0, stream>>>(x, z, W0, b0, b1, b2, b3, b4, wsH, y, N);
}

// Round 2
// 182.380 us; speedup vs baseline: 1.0709x; 1.0709x over previous
//
#include <hip/hip_runtime.h>

typedef _Float16 half8 __attribute__((ext_vector_type(8)));
typedef float    f32x4 __attribute__((ext_vector_type(4)));

// Fragment layout (validated in R1 by end-to-end pass):
//   value = Wsrc[k][m] held at lane l, elem j with
//   m = mt*16 + (l&15),  k = ks*32 + 16*(j>>2) + ((l>>4)<<2) + (j&3)
// ws layout (halfs): layer Li (i=1..3) W^T frags at (i-1)*16384, frag (mt*4+ks)*512 + lane*8
//                    W4^T frags at 49152 + ks*512 + lane*8

__global__ __launch_bounds__(256) void prep_kernel(
    const float* __restrict__ W1, const float* __restrict__ W2,
    const float* __restrict__ W3, const float* __restrict__ W4,
    _Float16* __restrict__ out)
{
    int t = blockIdx.x * blockDim.x + threadIdx.x;
    if (t >= 6400) return;
    int lane = t & 63;
    int frag = t >> 6;                 // 0..99
    const float* W; _Float16* dst; int mt, ks, dout;
    if (frag < 96) {
        int l = frag >> 5, f = frag & 31;
        W = (l == 0) ? W1 : (l == 1) ? W2 : W3;
        mt = f >> 2; ks = f & 3; dout = 128;
        dst = out + l * 16384 + f * 512 + lane * 8;
    } else {
        int f = frag - 96;
        W = W4; mt = 0; ks = f; dout = 14;
        dst = out + 49152 + f * 512 + lane * 8;
    }
    int m = mt * 16 + (lane & 15);          // output-feature index (row of W^T)
    int kbase = ks * 32 + ((lane >> 4) << 2);
#pragma unroll
    for (int j = 0; j < 8; ++j) {
        int k = kbase + 16 * (j >> 2) + (j & 3);   // input-feature index
        float v = (m < dout) ? W[k * dout + m] : 0.0f;
        dst[j] = (_Float16)v;
    }
}

__global__ __launch_bounds__(256, 2) void nflow_kernel(
    const float* __restrict__ x, const float* __restrict__ z,
    const float* __restrict__ W0, const float* __restrict__ b0,
    const float* __restrict__ b1, const float* __restrict__ b2,
    const float* __restrict__ b3, const float* __restrict__ b4v,
    const _Float16* __restrict__ Af, float* __restrict__ y, int N)
{
    __shared__ float phis[4][32][20];   // 10240 B, per-wave phi staging (stride 20 -> aligned b128)

    const int tid  = threadIdx.x;
    const int lane = tid & 63;
    const int wid  = tid >> 6;
    const int col  = lane & 15;
    const int quad = lane >> 4;
    const int sbase = blockIdx.x * 128 + wid * 32;
    const int s0 = sbase + col;

    half8 b[2][4];   // B-fragments of h: n = col (sample), k per fragment formula

    // ---- layer 0: h0 = relu(x*W0 + b0), built directly as B-fragments
    {
        float xv0 = (s0 < N)      ? x[s0]      : 0.0f;
        float xv1 = (s0 + 16 < N) ? x[s0 + 16] : 0.0f;
#pragma unroll
        for (int ks = 0; ks < 4; ++ks) {
            f32x4 wlo = *(const f32x4*)(W0 + ks * 32 + quad * 4);
            f32x4 whi = *(const f32x4*)(W0 + ks * 32 + 16 + quad * 4);
            f32x4 blo = *(const f32x4*)(b0 + ks * 32 + quad * 4);
            f32x4 bhi = *(const f32x4*)(b0 + ks * 32 + 16 + quad * 4);
#pragma unroll
            for (int e = 0; e < 4; ++e) {
                b[0][ks][e]     = (_Float16)fmaxf(fmaf(xv0, wlo[e], blo[e]), 0.0f);
                b[0][ks][e + 4] = (_Float16)fmaxf(fmaf(xv0, whi[e], bhi[e]), 0.0f);
                b[1][ks][e]     = (_Float16)fmaxf(fmaf(xv1, wlo[e], blo[e]), 0.0f);
                b[1][ks][e + 4] = (_Float16)fmaxf(fmaf(xv1, whi[e], bhi[e]), 0.0f);
            }
        }
    }

    // ---- hidden layers 1..3: acc[ni][mt] = W^T(mt) . h ; D cols are samples,
    //      D rows are output features -> directly the next layer's B-fragments.
#pragma unroll
    for (int l = 0; l < 3; ++l) {
        const _Float16* Al = Af + l * 16384;
        const float* bias = (l == 0) ? b1 : (l == 1) ? b2 : b3;

        f32x4 acc[2][8];
#pragma unroll
        for (int ni = 0; ni < 2; ++ni)
#pragma unroll
            for (int mt = 0; mt < 8; ++mt)
                acc[ni][mt] = (f32x4){0.f, 0.f, 0.f, 0.f};

        // ks-outer: 16 independent MFMAs per ks (acc dependence distance = 16)
#pragma unroll
        for (int ks = 0; ks < 4; ++ks) {
#pragma unroll
            for (int mt = 0; mt < 8; ++mt) {
                half8 a = *(const half8*)(Al + (mt * 4 + ks) * 512 + lane * 8);
                acc[0][mt] = __builtin_amdgcn_mfma_f32_16x16x32_f16(a, b[0][ks], acc[0][mt], 0, 0, 0);
                acc[1][mt] = __builtin_amdgcn_mfma_f32_16x16x32_f16(a, b[1][ks], acc[1][mt], 0, 0, 0);
            }
        }

        // bias + relu + cvt: rebuild B-fragments in-register (lane-local!)
        f32x4 bv[8];
#pragma unroll
        for (int mt = 0; mt < 8; ++mt)
            bv[mt] = *(const f32x4*)(bias + mt * 16 + quad * 4);
#pragma unroll
        for (int ni = 0; ni < 2; ++ni)
#pragma unroll
            for (int ks = 0; ks < 4; ++ks)
#pragma unroll
                for (int j = 0; j < 8; ++j) {
                    int mt = 2 * ks + (j >> 2), r = j & 3;
                    b[ni][ks][j] = (_Float16)fmaxf(acc[ni][mt][r] + bv[mt][r], 0.0f);
                }
    }

    // ---- layer 4: phi = W4^T . h  (14 outputs, padded to 16)
    {
        f32x4 acc4[2];
        acc4[0] = (f32x4){0.f, 0.f, 0.f, 0.f};
        acc4[1] = (f32x4){0.f, 0.f, 0.f, 0.f};
#pragma unroll
        for (int ks = 0; ks < 4; ++ks) {
            half8 a = *(const half8*)(Af + 49152 + ks * 512 + lane * 8);
            acc4[0] = __builtin_amdgcn_mfma_f32_16x16x32_f16(a, b[0][ks], acc4[0], 0, 0, 0);
            acc4[1] = __builtin_amdgcn_mfma_f32_16x16x32_f16(a, b[1][ks], acc4[1], 0, 0, 0);
        }
        float bb[4];
#pragma unroll
        for (int r = 0; r < 4; ++r) {
            int comp = quad * 4 + r;
            bb[r] = (comp < 14) ? b4v[comp] : 0.0f;
        }
#pragma unroll
        for (int ni = 0; ni < 2; ++ni) {
            f32x4 v;
#pragma unroll
            for (int r = 0; r < 4; ++r) v[r] = acc4[ni][r] + bb[r];
            *(f32x4*)&phis[wid][ni * 16 + col][quad * 4] = v;
        }
    }

    __syncthreads();

    // ---- RQS inverse: lanes 0..31 of each wave handle its 32 samples
    if (lane < 32) {
        int gs = sbase + lane;
        if (gs < N) {
            float ph[16];
            *(f32x4*)&ph[0]  = *(const f32x4*)&phis[wid][lane][0];
            *(f32x4*)&ph[4]  = *(const f32x4*)&phis[wid][lane][4];
            *(f32x4*)&ph[8]  = *(const f32x4*)&phis[wid][lane][8];
            *(f32x4*)&ph[12] = *(const f32x4*)&phis[wid][lane][12];

            float mw = ph[0], mh = ph[5];
#pragma unroll
            for (int i = 1; i < 5; ++i) { mw = fmaxf(mw, ph[i]); mh = fmaxf(mh, ph[5 + i]); }
            float ew[5], eh[5];
            float sw = 0.f, sh = 0.f;
#pragma unroll
            for (int i = 0; i < 5; ++i) {
                ew[i] = expf(ph[i] - mw);      sw += ew[i];
                eh[i] = expf(ph[5 + i] - mh);  sh += eh[i];
            }
            float iw = 10.0f / sw, ih = 10.0f / sh;
            float xk[6], yk[6], dk[6];
            xk[0] = -5.0f; yk[0] = -5.0f;
#pragma unroll
            for (int i = 0; i < 5; ++i) {
                xk[i + 1] = xk[i] + ew[i] * iw;
                yk[i + 1] = yk[i] + eh[i] * ih;
            }
            dk[0] = 1.0f; dk[5] = 1.0f;
#pragma unroll
            for (int i = 0; i < 4; ++i) {
                float v = ph[10 + i];
                dk[i + 1] = 0.0001f + fmaxf(v, 0.0f) + log1pf(expf(-fabsf(v)));
            }
            float zv = z[gs];
            float zc = fminf(fmaxf(zv, -5.0f), 5.0f);
            int k = 0;
#pragma unroll
            for (int i = 1; i <= 4; ++i) k += (zc >= yk[i]) ? 1 : 0;
            float x0 = xk[0], x1 = xk[1], y0 = yk[0], y1 = yk[1], d0 = dk[0], d1 = dk[1];
#pragma unroll
            for (int i = 1; i < 5; ++i)
                if (k == i) { x0 = xk[i]; x1 = xk[i + 1]; y0 = yk[i]; y1 = yk[i + 1]; d0 = dk[i]; d1 = dk[i + 1]; }
            float dx = x1 - x0, dy = y1 - y0;
            float s  = dy / dx;
            float tt = zc - y0;
            float mm = d0 + d1 - 2.0f * s;
            float aa = dy * (s - d0) + tt * mm;
            float bb2 = dy * d0 - tt * mm;
            float cc = -s * tt;
            float disc = fmaxf(bb2 * bb2 - 4.0f * aa * cc, 0.0f);
            float xi   = (2.0f * cc) / (-bb2 - sqrtf(disc));
            float xin  = x0 + xi * dx;
            y[gs] = (fabsf(zv) >= 5.0f) ? zv : xin;
        }
    }
}

extern "C" void kernel_launch(void* const* d_in, const int* in_sizes, int n_in,
                              void* d_out, int out_size, void* d_ws, size_t ws_size,
                              hipStream_t stream) {
    const float* x  = (const float*)d_in[0];
    const float* z  = (const float*)d_in[1];
    const float* W0 = (const float*)d_in[2];
    const float* b0 = (const float*)d_in[3];
    const float* W1 = (const float*)d_in[4];
    const float* b1 = (const float*)d_in[5];
    const float* W2 = (const float*)d_in[6];
    const float* b2 = (const float*)d_in[7];
    const float* W3 = (const float*)d_in[8];
    const float* b3 = (const float*)d_in[9];
    const float* W4 = (const float*)d_in[10];
    const float* b4 = (const float*)d_in[11];
    float* y = (float*)d_out;
    int N = in_sizes[0];

    _Float16* wsH = (_Float16*)d_ws;
    prep_kernel<<<25, 256, 0, stream>>>(W1, W2, W3, W4, wsH);
    int nblk = (N + 127) / 128;
    nflow_kernel<<<nblk, 256, 0, stream>>>(x, z, W0, b0, b1, b2, b3, b4, wsH, y, N);
}

// Round 4
// 155.831 us; speedup vs baseline: 1.2534x; 1.1704x over previous
//
#include <hip/hip_runtime.h>

typedef _Float16 half8 __attribute__((ext_vector_type(8)));
typedef _Float16 half2v __attribute__((ext_vector_type(2)));
typedef __fp16   fp16x2 __attribute__((ext_vector_type(2)));
typedef float    f32x4 __attribute__((ext_vector_type(4)));

// Fragment layout (validated R1/R2 end-to-end):
//   value = Wsrc[k][m] at lane l, elem j:  m = mt*16 + (l&15),
//   k = ks*32 + 16*(j>>2) + ((l>>4)<<2) + (j&3)
// ws (halfs): L1..L3 W^T frags at (i-1)*16384 + (mt*4+ks)*512 + lane*8
//             W4^T at 49152 + ks*512 + lane*8
//             W0ext (k=0 row -> W0, k=1 row -> b0) at 53248 + mt*512 + lane*8

__global__ __launch_bounds__(256) void prep_kernel(
    const float* __restrict__ W1, const float* __restrict__ W2,
    const float* __restrict__ W3, const float* __restrict__ W4,
    const float* __restrict__ W0, const float* __restrict__ b0,
    _Float16* __restrict__ out)
{
    int t = blockIdx.x * blockDim.x + threadIdx.x;
    if (t >= 6912) return;
    int lane = t & 63;
    int frag = t >> 6;                 // 0..107
    int col  = lane & 15;
    int kq   = (lane >> 4) << 2;

    if (frag < 96) {
        int l = frag >> 5, f = frag & 31;
        const float* W = (l == 0) ? W1 : (l == 1) ? W2 : W3;
        int mt = f >> 2, ks = f & 3;
        _Float16* dst = out + l * 16384 + f * 512 + lane * 8;
        int m = mt * 16 + col;
        int kbase = ks * 32 + kq;
#pragma unroll
        for (int j = 0; j < 8; ++j) {
            int k = kbase + 16 * (j >> 2) + (j & 3);
            dst[j] = (_Float16)W[k * 128 + m];
        }
    } else if (frag < 100) {
        int ks = frag - 96;
        _Float16* dst = out + 49152 + ks * 512 + lane * 8;
        int m = col;
        int kbase = ks * 32 + kq;
#pragma unroll
        for (int j = 0; j < 8; ++j) {
            int k = kbase + 16 * (j >> 2) + (j & 3);
            float v = (m < 14) ? W4[k * 14 + m] : 0.0f;
            dst[j] = (_Float16)v;
        }
    } else {
        int mt = frag - 100;
        _Float16* dst = out + 53248 + mt * 512 + lane * 8;
        int m = mt * 16 + col;
#pragma unroll
        for (int j = 0; j < 8; ++j) {
            int k = 16 * (j >> 2) + kq + (j & 3);
            float v = (k == 0) ? W0[m] : (k == 1) ? b0[m] : 0.0f;
            dst[j] = (_Float16)v;
        }
    }
}

static __device__ __forceinline__ half2v relu_cvt2(float a, float b) {
    fp16x2 h = __builtin_amdgcn_cvt_pkrtz(a, b);
    fp16x2 zz = {(__fp16)0.0f, (__fp16)0.0f};
    h = __builtin_elementwise_max(h, zz);
    return __builtin_bit_cast(half2v, h);
}

__global__ __launch_bounds__(256, 2) void nflow_kernel(
    const float* __restrict__ x, const float* __restrict__ z,
    const float* __restrict__ b1, const float* __restrict__ b2,
    const float* __restrict__ b3, const float* __restrict__ b4v,
    const _Float16* __restrict__ Af, float* __restrict__ y, int N)
{
    __shared__ float phis[4][32][20];   // 10240 B, stride 20 -> conflict-free b128

    const int tid  = threadIdx.x;
    const int lane = tid & 63;
    const int wid  = tid >> 6;
    const int col  = lane & 15;
    const int quad = lane >> 4;
    const int sbase = blockIdx.x * 128 + wid * 32;
    const int s0 = sbase + col;

    half8 b[2][4];   // B-fragments of h (samples on N)

    // ---- layer 0 as MFMA: h0 = relu([x,1]·[W0;b0])
    {
        float xv0 = (s0 < N)      ? x[s0]      : 0.0f;
        float xv1 = (s0 + 16 < N) ? x[s0 + 16] : 0.0f;
        half8 bx0 = {}, bx1 = {};
        if (quad == 0) {
            bx0[0] = (_Float16)xv0; bx0[1] = (_Float16)1.0f;
            bx1[0] = (_Float16)xv1; bx1[1] = (_Float16)1.0f;
        }
        f32x4 acc[2][8];
#pragma unroll
        for (int mt = 0; mt < 8; ++mt) {
            half8 a = *(const half8*)(Af + 53248 + mt * 512 + lane * 8);
            acc[0][mt] = __builtin_amdgcn_mfma_f32_16x16x32_f16(a, bx0, (f32x4){0.f,0.f,0.f,0.f}, 0, 0, 0);
            acc[1][mt] = __builtin_amdgcn_mfma_f32_16x16x32_f16(a, bx1, (f32x4){0.f,0.f,0.f,0.f}, 0, 0, 0);
        }
#pragma unroll
        for (int ni = 0; ni < 2; ++ni)
#pragma unroll
            for (int ks = 0; ks < 4; ++ks)
#pragma unroll
                for (int p = 0; p < 4; ++p) {
                    int mt = 2 * ks + (p >> 1), r = 2 * (p & 1);
                    half2v h = relu_cvt2(acc[ni][mt][r], acc[ni][mt][r + 1]);
                    b[ni][ks][2 * p]     = h[0];
                    b[ni][ks][2 * p + 1] = h[1];
                }
    }

    // ---- hidden layers 1..3 (bias folded into acc init)
#pragma unroll
    for (int l = 0; l < 3; ++l) {
        const _Float16* Al = Af + l * 16384;
        const float* bias = (l == 0) ? b1 : (l == 1) ? b2 : b3;

        f32x4 acc[2][8];
#pragma unroll
        for (int mt = 0; mt < 8; ++mt) {
            f32x4 bv = *(const f32x4*)(bias + mt * 16 + quad * 4);
            acc[0][mt] = bv;
            acc[1][mt] = bv;
        }

#pragma unroll
        for (int ks = 0; ks < 4; ++ks) {
#pragma unroll
            for (int mt = 0; mt < 8; ++mt) {
                half8 a = *(const half8*)(Al + (mt * 4 + ks) * 512 + lane * 8);
                acc[0][mt] = __builtin_amdgcn_mfma_f32_16x16x32_f16(a, b[0][ks], acc[0][mt], 0, 0, 0);
                acc[1][mt] = __builtin_amdgcn_mfma_f32_16x16x32_f16(a, b[1][ks], acc[1][mt], 0, 0, 0);
            }
        }

#pragma unroll
        for (int ni = 0; ni < 2; ++ni)
#pragma unroll
            for (int ks = 0; ks < 4; ++ks)
#pragma unroll
                for (int p = 0; p < 4; ++p) {
                    int mt = 2 * ks + (p >> 1), r = 2 * (p & 1);
                    half2v h = relu_cvt2(acc[ni][mt][r], acc[ni][mt][r + 1]);
                    b[ni][ks][2 * p]     = h[0];
                    b[ni][ks][2 * p + 1] = h[1];
                }
    }

    // ---- layer 4: phi = W4^T·h + b4 (bias in acc init)
    {
        f32x4 bbv;
#pragma unroll
        for (int r = 0; r < 4; ++r) {
            int comp = quad * 4 + r;
            bbv[r] = (comp < 14) ? b4v[comp] : 0.0f;
        }
        f32x4 acc4[2] = {bbv, bbv};
#pragma unroll
        for (int ks = 0; ks < 4; ++ks) {
            half8 a = *(const half8*)(Af + 49152 + ks * 512 + lane * 8);
            acc4[0] = __builtin_amdgcn_mfma_f32_16x16x32_f16(a, b[0][ks], acc4[0], 0, 0, 0);
            acc4[1] = __builtin_amdgcn_mfma_f32_16x16x32_f16(a, b[1][ks], acc4[1], 0, 0, 0);
        }
#pragma unroll
        for (int ni = 0; ni < 2; ++ni)
            *(f32x4*)&phis[wid][ni * 16 + col][quad * 4] = acc4[ni];
    }

    __syncthreads();

    // ---- RQS inverse (lanes 0..31 per wave; fast transcendentals)
    if (lane < 32) {
        int gs = sbase + lane;
        if (gs < N) {
            float ph[16];
            *(f32x4*)&ph[0]  = *(const f32x4*)&phis[wid][lane][0];
            *(f32x4*)&ph[4]  = *(const f32x4*)&phis[wid][lane][4];
            *(f32x4*)&ph[8]  = *(const f32x4*)&phis[wid][lane][8];
            *(f32x4*)&ph[12] = *(const f32x4*)&phis[wid][lane][12];

            float mw = ph[0], mh = ph[5];
#pragma unroll
            for (int i = 1; i < 5; ++i) { mw = fmaxf(mw, ph[i]); mh = fmaxf(mh, ph[5 + i]); }
            float ew[5], eh[5];
            float sw = 0.f, sh = 0.f;
#pragma unroll
            for (int i = 0; i < 5; ++i) {
                ew[i] = __expf(ph[i] - mw);      sw += ew[i];
                eh[i] = __expf(ph[5 + i] - mh);  sh += eh[i];
            }
            float iw = 10.0f / sw, ih = 10.0f / sh;
            float xk[6], yk[6], dk[6];
            xk[0] = -5.0f; yk[0] = -5.0f;
#pragma unroll
            for (int i = 0; i < 5; ++i) {
                xk[i + 1] = xk[i] + ew[i] * iw;
                yk[i + 1] = yk[i] + eh[i] * ih;
            }
            dk[0] = 1.0f; dk[5] = 1.0f;
#pragma unroll
            for (int i = 0; i < 4; ++i) {
                float v = ph[10 + i];
                dk[i + 1] = 0.0001f + fmaxf(v, 0.0f) + __logf(1.0f + __expf(-fabsf(v)));
            }
            float zv = z[gs];
            float zc = fminf(fmaxf(zv, -5.0f), 5.0f);
            int k = 0;
#pragma unroll
            for (int i = 1; i <= 4; ++i) k += (zc >= yk[i]) ? 1 : 0;
            float x0 = xk[0], x1 = xk[1], y0 = yk[0], y1 = yk[1], d0 = dk[0], d1 = dk[1];
#pragma unroll
            for (int i = 1; i < 5; ++i)
                if (k == i) { x0 = xk[i]; x1 = xk[i + 1]; y0 = yk[i]; y1 = yk[i + 1]; d0 = dk[i]; d1 = dk[i + 1]; }
            float dx = x1 - x0, dy = y1 - y0;
            float s  = dy / dx;
            float tt = zc - y0;
            float mm = d0 + d1 - 2.0f * s;
            float aa = dy * (s - d0) + tt * mm;
            float bb2 = dy * d0 - tt * mm;
            float cc = -s * tt;
            float disc = fmaxf(bb2 * bb2 - 4.0f * aa * cc, 0.0f);
            float xi   = (2.0f * cc) / (-bb2 - sqrtf(disc));
            float xin  = x0 + xi * dx;
            y[gs] = (fabsf(zv) >= 5.0f) ? zv : xin;
        }
    }
}

extern "C" void kernel_launch(void* const* d_in, const int* in_sizes, int n_in,
                              void* d_out, int out_size, void* d_ws, size_t ws_size,
                              hipStream_t stream) {
    const float* x  = (const float*)d_in[0];
    const float* z  = (const float*)d_in[1];
    const float* W0 = (const float*)d_in[2];
    const float* b0 = (const float*)d_in[3];
    const float* W1 = (const float*)d_in[4];
    const float* b1 = (const float*)d_in[5];
    const float* W2 = (const float*)d_in[6];
    const float* b2 = (const float*)d_in[7];
    const float* W3 = (const float*)d_in[8];
    const float* b3 = (const float*)d_in[9];
    const float* W4 = (const float*)d_in[10];
    const float* b4 = (const float*)d_in[11];
    float* y = (float*)d_out;
    int N = in_sizes[0];

    _Float16* wsH = (_Float16*)d_ws;
    prep_kernel<<<27, 256, 0, stream>>>(W1, W2, W3, W4, W0, b0, wsH);
    int nblk = (N + 127) / 128;
    nflow_kernel<<<nblk, 256, 0, stream>>>(x, z, b1, b2, b3, b4, wsH, y, N);
}